// Round 5
// baseline (510.547 us; speedup 1.0000x reference)
//
#include <hip/hip_runtime.h>

// GraphAttention on MI355X (gfx950).  B=2, S=2048, E=1024, H=16, D=64.
// Round 5: attn k-loop goes barrier-free — K/V fragments loaded per-lane from
// global (L1/L2-cached; identical contents to the old LDS staging), bias via
// pre-transposed bias_t[b][k][q] ushort4 loads. Only Qs (once) + per-wave Ps
// remain in LDS. Fixes the measured 16-way Ks-read bank conflicts (1.79e7).

typedef unsigned short ushort_t;
typedef __attribute__((ext_vector_type(8))) short bf16x8;
typedef __attribute__((ext_vector_type(4))) float floatx4;

#define NB 2
#define NS 2048
#define NE 1024
#define NH 16
#define ND 64

__device__ __forceinline__ unsigned short f2bf(float f) {
  unsigned int u = __float_as_uint(f);
  return (unsigned short)((u + 0x7fffu + ((u >> 16) & 1u)) >> 16);
}
__device__ __forceinline__ float bf2f(unsigned short h) {
  return __uint_as_float(((unsigned int)h) << 16);
}

__device__ __forceinline__ void gload_lds16(const void* g, void* l) {
  __builtin_amdgcn_global_load_lds(
      (const __attribute__((address_space(1))) unsigned int*)g,
      (__attribute__((address_space(3))) unsigned int*)l, 16, 0, 0);
}

// ---------------------------------------------------------------------------
// Kernel 1: fp32->bf16 conversions (q,k,v,Wq,Wk,Wv,Wo). unit = 8 elements.
// 3*524288 + 4*131072 = 2097152 units = 8192 blocks * 256.
// ---------------------------------------------------------------------------
__global__ __launch_bounds__(256) void convert_kernel(
    const float* __restrict__ q, const float* __restrict__ k, const float* __restrict__ v,
    const float* __restrict__ wq, const float* __restrict__ wk,
    const float* __restrict__ wv, const float* __restrict__ wo,
    ushort_t* __restrict__ qb, ushort_t* __restrict__ kb, ushort_t* __restrict__ vb,
    ushort_t* __restrict__ wqb, ushort_t* __restrict__ wkb,
    ushort_t* __restrict__ wvb, ushort_t* __restrict__ wob)
{
  const long U1 = (long)NB * NS * NE / 8;  // 524288
  const long U2 = (long)NE * NE / 8;       // 131072
  long idx = (long)blockIdx.x * 256 + threadIdx.x;
  const float* src;
  ushort_t* dst;
  if (idx < U1) { src = q; dst = qb; }
  else if ((idx -= U1) < U1) { src = k; dst = kb; }
  else if ((idx -= U1) < U1) { src = v; dst = vb; }
  else if ((idx -= U1) < U2) { src = wq; dst = wqb; }
  else if ((idx -= U2) < U2) { src = wk; dst = wkb; }
  else if ((idx -= U2) < U2) { src = wv; dst = wvb; }
  else { idx -= U2; src = wo; dst = wob; }
  const float4* s4 = (const float4*)src;
  float4 a0 = s4[idx * 2], a1 = s4[idx * 2 + 1];
  union { ushort_t us[8]; uint4 v4; } o;
  o.us[0] = f2bf(a0.x); o.us[1] = f2bf(a0.y); o.us[2] = f2bf(a0.z); o.us[3] = f2bf(a0.w);
  o.us[4] = f2bf(a1.x); o.us[5] = f2bf(a1.y); o.us[6] = f2bf(a1.z); o.us[7] = f2bf(a1.w);
  ((uint4*)dst)[idx] = o.v4;
}

// ---------------------------------------------------------------------------
// Kernel 2: bias_t[b][k][q] = bf16( mask[b][q][k] ? adj[q][k] : -1e30 ).
// 64x64 tile transpose through LDS; coalesced loads and stores. Linear space.
// Grid (32 ktiles, 32 qtiles, 2 b), block 256.
// ---------------------------------------------------------------------------
__global__ __launch_bounds__(256) void bias_kernel(
    const float* __restrict__ adj, const int* __restrict__ mask,
    ushort_t* __restrict__ bias_t)
{
  __shared__ ushort_t Ts[64][68];
  int t = threadIdx.x;
  int k0 = blockIdx.x * 64, q0 = blockIdx.y * 64, b = blockIdx.z;
  const long mbase = (long)b * NS * NS;
  int qr = t >> 4;
  int kc = (t & 15) * 4;
#pragma unroll
  for (int rr = 0; rr < 4; rr++) {
    int qq = qr + rr * 16;
    float4 a = *(const float4*)(adj + (long)(q0 + qq) * NS + k0 + kc);
    int4 m = *(const int4*)(mask + mbase + (long)(q0 + qq) * NS + k0 + kc);
    ushort4 o;
    o.x = f2bf(m.x ? a.x : -1e30f);
    o.y = f2bf(m.y ? a.y : -1e30f);
    o.z = f2bf(m.z ? a.z : -1e30f);
    o.w = f2bf(m.w ? a.w : -1e30f);
    *(ushort4*)(&Ts[qq][kc]) = o;
  }
  __syncthreads();
  int kr = t >> 4;
  int qc = (t & 15) * 4;
#pragma unroll
  for (int rr = 0; rr < 4; rr++) {
    int kk = kr + rr * 16;
    ushort4 o;
    o.x = Ts[qc + 0][kk];
    o.y = Ts[qc + 1][kk];
    o.z = Ts[qc + 2][kk];
    o.w = Ts[qc + 3][kk];
    *(ushort4*)(bias_t + mbase + (long)(k0 + kk) * NS + q0 + qc) = o;
  }
}

// ---------------------------------------------------------------------------
// Kernel 3: fused QKV projection GEMM (round-1 proven).
// ---------------------------------------------------------------------------
__global__ __launch_bounds__(256) void qkv_kernel(
    const ushort_t* __restrict__ xq, const ushort_t* __restrict__ xk, const ushort_t* __restrict__ xv,
    const ushort_t* __restrict__ wqb, const ushort_t* __restrict__ wkb, const ushort_t* __restrict__ wvb,
    const float* __restrict__ bq, const float* __restrict__ bk, const float* __restrict__ bvv,
    ushort_t* __restrict__ Qh, ushort_t* __restrict__ Kh, ushort_t* __restrict__ Vt)
{
  __shared__ __align__(16) ushort_t As[128 * 32];
  __shared__ __align__(16) ushort_t Bs[128 * 32];

  int z = blockIdx.z;
  const ushort_t* X = (z == 0) ? xq : (z == 1) ? xk : xv;
  const ushort_t* W = (z == 0) ? wqb : (z == 1) ? wkb : wvb;
  const float* bias = (z == 0) ? bq : (z == 1) ? bk : bvv;

  int t = threadIdx.x;
  int lane = t & 63, w = t >> 6;
  int quad = lane >> 4, l16 = lane & 15;
  int wr = w >> 1, wc = w & 1;
  int m0 = blockIdx.y * 128, f0 = blockIdx.x * 128;

  floatx4 acc[4][4] = {};

  int arow = t >> 2, apart = t & 3;
  const ushort_t* Xg = X + (long)(m0 + arow) * NE + apart * 8;
  const ushort_t* Wg = W + (long)(f0 + arow) * NE + apart * 8;
  ushort_t* As_t = As + t * 8;
  ushort_t* Bs_t = Bs + t * 8;

  for (int k0 = 0; k0 < NE; k0 += 32) {
    __syncthreads();
    gload_lds16(Xg + k0, As_t);
    gload_lds16(Xg + k0 + 64 * NE, As_t + 64 * 32);
    gload_lds16(Wg + k0, Bs_t);
    gload_lds16(Wg + k0 + 64 * NE, Bs_t + 64 * 32);
    __syncthreads();
    bf16x8 af[4], bf[4];
#pragma unroll
    for (int i = 0; i < 4; i++)
      af[i] = *(const bf16x8*)(As + (wr * 64 + i * 16 + l16) * 32 + quad * 8);
#pragma unroll
    for (int j = 0; j < 4; j++)
      bf[j] = *(const bf16x8*)(Bs + (wc * 64 + j * 16 + l16) * 32 + quad * 8);
#pragma unroll
    for (int i = 0; i < 4; i++)
#pragma unroll
      for (int j = 0; j < 4; j++)
        acc[i][j] = __builtin_amdgcn_mfma_f32_16x16x32_bf16(af[i], bf[j], acc[i][j], 0, 0, 0);
  }

  ushort_t* Out = (z == 0) ? Qh : (z == 1) ? Kh : Vt;
  bool isV = (z == 2);
#pragma unroll
  for (int j = 0; j < 4; j++) {
    int f = f0 + wc * 64 + j * 16 + l16;
    float bval = bias[f];
    int h = f >> 6, d = f & 63;
#pragma unroll
    for (int i = 0; i < 4; i++) {
      int mbase = m0 + wr * 64 + i * 16 + quad * 4;
#pragma unroll
      for (int r = 0; r < 4; r++) {
        int m = mbase + r;
        int b = m >> 11, s = m & 2047;
        float y = acc[i][j][r] + bval;
        long off;
        if (!isV) off = ((long)(b * NH + h) * NS + s) * ND + d;       // [B,H,S,D]
        else      off = ((long)(b * NH + h) * ND + d) * NS + s;       // [B,H,D,S]
        Out[off] = f2bf(y);
      }
    }
  }
}

// ---------------------------------------------------------------------------
// Kernel 4: flash attention, max-free, barrier-free k-loop.
// Block 256 (4 waves), q-tile 64 (16 rows/wave), k-tiles of 32.
// K/V fragments: per-lane 16B global loads (same contents as old LDS staging).
// Bias: 2x ushort4 loads from bias_t[b][k][q].
// Only Qs (staged once) and per-wave Ps (stride 72) live in LDS.
// Grid (32 qt, 32 bh) = 1024 blocks = 4 blocks/CU.
// ---------------------------------------------------------------------------
__global__ __launch_bounds__(256, 4) void attn_kernel(
    const ushort_t* __restrict__ Qh, const ushort_t* __restrict__ Kh,
    const ushort_t* __restrict__ Vt, const ushort_t* __restrict__ bias_t,
    ushort_t* __restrict__ aout)
{
  __shared__ __align__(16) ushort_t Qs[64 * 64];     // 8KB
  __shared__ __align__(16) ushort_t Ps[4][16 * 72];  // 9KB (per-wave, stride 72)

  int t = threadIdx.x, lane = t & 63, w = t >> 6;
  int quad = lane >> 4, l16 = lane & 15;
  int qt = blockIdx.x;       // q-tile 0..31
  int bh = blockIdx.y;       // 0..31
  int bb = bh >> 4, h = bh & 15;
  int q0 = qt * 64;

  // stage Q tile (once): 64 rows x 64 cols = 512 x 16B chunks, 2 per thread
  const ushort_t* Qg = Qh + ((long)bh * NS + q0) * ND;
#pragma unroll
  for (int c = 0; c < 2; c++) {
    int idx = c * 256 + t;
    int row = idx >> 3, part = idx & 7;
    gload_lds16(Qg + (long)row * ND + part * 8, Qs + idx * 8);
  }
  __syncthreads();

  bf16x8 aq[2];
#pragma unroll
  for (int kd = 0; kd < 2; kd++)
    aq[kd] = *(const bf16x8*)(Qs + (w * 16 + l16) * 64 + kd * 32 + quad * 8);

  floatx4 acc[4] = {};
  float lsum[4] = {0.f, 0.f, 0.f, 0.f};

  // per-lane invariant fragment base pointers
  const ushort_t* Kf = Kh + (long)bh * NS * ND + (long)l16 * ND + quad * 8;
  const ushort_t* Vf = Vt + (long)bh * ND * NS + (long)l16 * NS + quad * 8;
  const ushort_t* Bf = bias_t + (long)bb * NS * NS + (long)l16 * NS
                       + q0 + w * 16 + quad * 4;
  ushort_t* Psw = &Ps[w][0];

  for (int kt = 0; kt < NS / 32; kt++) {
    int k0 = kt * 32;

    // K fragments: bk[jk][kd] lane view = K[k0+jk*16+l16][kd*32+quad*8 ..+8]
    bf16x8 bk[2][2];
#pragma unroll
    for (int jk = 0; jk < 2; jk++)
#pragma unroll
      for (int kd = 0; kd < 2; kd++)
        bk[jk][kd] = *(const bf16x8*)(Kf + (long)(k0 + jk * 16) * ND + kd * 32);

    // V fragments: bv[j] lane view = Vt[j*16+l16][k0+quad*8 ..+8]
    bf16x8 bv[4];
#pragma unroll
    for (int j = 0; j < 4; j++)
      bv[j] = *(const bf16x8*)(Vf + (long)(j * 16) * NS + k0);

    // bias: bsa[jk][r] = bias[q0+w*16+quad*4+r][k0+jk*16+l16]
    ushort_t bsa[2][4];
    *(ushort4*)bsa[0] = *(const ushort4*)(Bf + (long)k0 * NS);
    *(ushort4*)bsa[1] = *(const ushort4*)(Bf + (long)(k0 + 16) * NS);

    // scores = Q K^T  (C rows: q = quad*4 + r, cols: k = jk*16 + l16)
    floatx4 sc[2] = {};
#pragma unroll
    for (int jk = 0; jk < 2; jk++)
#pragma unroll
      for (int kd = 0; kd < 2; kd++)
        sc[jk] = __builtin_amdgcn_mfma_f32_16x16x32_bf16(aq[kd], bk[jk][kd], sc[jk], 0, 0, 0);

    // p = exp(sc/8 + bias); no running max (bounded scores)
    float p[2][4];
#pragma unroll
    for (int r = 0; r < 4; r++) {
      float s0 = sc[0][r] * 0.125f + bf2f(bsa[0][r]);
      float s1 = sc[1][r] * 0.125f + bf2f(bsa[1][r]);
      float p0 = __expf(s0);
      float p1 = __expf(s1);
      lsum[r] += p0 + p1;
      p[0][r] = p0;
      p[1][r] = p1;
    }

    // P: C/D layout -> per-wave LDS (stride 72) -> A layout
#pragma unroll
    for (int jk = 0; jk < 2; jk++)
#pragma unroll
      for (int r = 0; r < 4; r++)
        Psw[(quad * 4 + r) * 72 + jk * 16 + l16] = f2bf(p[jk][r]);
    asm volatile("s_waitcnt lgkmcnt(0)" ::: "memory");

    bf16x8 ap = *(const bf16x8*)(Psw + l16 * 72 + quad * 8);
#pragma unroll
    for (int j = 0; j < 4; j++)
      acc[j] = __builtin_amdgcn_mfma_f32_16x16x32_bf16(ap, bv[j], acc[j], 0, 0, 0);
  }

  // deferred row-sum reduction: butterfly over l16 (rows live in quad groups)
#pragma unroll
  for (int r = 0; r < 4; r++) {
    float s = lsum[r];
    s += __shfl_xor(s, 1);
    s += __shfl_xor(s, 2);
    s += __shfl_xor(s, 4);
    s += __shfl_xor(s, 8);
    lsum[r] = s;
  }

  // epilogue: O / l -> aout [B,S,E] bf16
  ushort_t* og = aout + (long)bb * NS * NE + h * ND;
#pragma unroll
  for (int r = 0; r < 4; r++) {
    int qg = q0 + w * 16 + quad * 4 + r;
    float inv = 1.0f / lsum[r];
#pragma unroll
    for (int j = 0; j < 4; j++) {
      int d = j * 16 + l16;
      og[(long)qg * NE + d] = f2bf(acc[j][r] * inv);
    }
  }
}

// ---------------------------------------------------------------------------
// Kernel 5: output projection. out = aout @ Wo^T + bo, fp32 stores.
// 128m x 64n tiles, grid (16, 32) = 512 blocks = 2/CU.
// ---------------------------------------------------------------------------
__global__ __launch_bounds__(256) void oproj_kernel(
    const ushort_t* __restrict__ A, const ushort_t* __restrict__ Wob,
    const float* __restrict__ bo, float* __restrict__ out)
{
  __shared__ __align__(16) ushort_t As[128 * 32];  // 8KB
  __shared__ __align__(16) ushort_t Bs[64 * 32];   // 4KB

  int t = threadIdx.x;
  int lane = t & 63, w = t >> 6;
  int quad = lane >> 4, l16 = lane & 15;
  int wr = w >> 1, wc = w & 1;
  int m0 = blockIdx.y * 128, f0 = blockIdx.x * 64;

  floatx4 acc[4][2] = {};
  int arow = t >> 2, apart = t & 3;
  const ushort_t* Xg = A + (long)(m0 + arow) * NE + apart * 8;
  const ushort_t* Wg = Wob + (long)(f0 + arow) * NE + apart * 8;
  ushort_t* As_t = As + t * 8;
  ushort_t* Bs_t = Bs + t * 8;
  bool bstage = (arow < 64);

  for (int k0 = 0; k0 < NE; k0 += 32) {
    __syncthreads();
    gload_lds16(Xg + k0, As_t);
    gload_lds16(Xg + k0 + 64 * NE, As_t + 64 * 32);
    if (bstage) gload_lds16(Wg + k0, Bs_t);
    __syncthreads();
    bf16x8 af[4], bf[2];
#pragma unroll
    for (int i = 0; i < 4; i++)
      af[i] = *(const bf16x8*)(As + (wr * 64 + i * 16 + l16) * 32 + quad * 8);
#pragma unroll
    for (int j = 0; j < 2; j++)
      bf[j] = *(const bf16x8*)(Bs + (wc * 32 + j * 16 + l16) * 32 + quad * 8);
#pragma unroll
    for (int i = 0; i < 4; i++)
#pragma unroll
      for (int j = 0; j < 2; j++)
        acc[i][j] = __builtin_amdgcn_mfma_f32_16x16x32_bf16(af[i], bf[j], acc[i][j], 0, 0, 0);
  }

#pragma unroll
  for (int j = 0; j < 2; j++) {
    int f = f0 + wc * 32 + j * 16 + l16;
    float bval = bo[f];
#pragma unroll
    for (int i = 0; i < 4; i++) {
      int mbase = m0 + wr * 64 + i * 16 + quad * 4;
#pragma unroll
      for (int r = 0; r < 4; r++) {
        int m = mbase + r;
        out[(long)m * NE + f] = acc[i][j][r] + bval;
      }
    }
  }
}

// ---------------------------------------------------------------------------
extern "C" void kernel_launch(void* const* d_in, const int* in_sizes, int n_in,
                              void* d_out, int out_size, void* d_ws, size_t ws_size,
                              hipStream_t stream) {
  const float* query = (const float*)d_in[0];
  const float* key   = (const float*)d_in[1];
  const float* value = (const float*)d_in[2];
  const float* adj   = (const float*)d_in[3];
  const int*   mask  = (const int*)d_in[4];
  const float* Wq = (const float*)d_in[5];
  const float* bq = (const float*)d_in[6];
  const float* Wk = (const float*)d_in[7];
  const float* bk = (const float*)d_in[8];
  const float* Wv = (const float*)d_in[9];
  const float* bv = (const float*)d_in[10];
  const float* Wo = (const float*)d_in[11];
  const float* bo = (const float*)d_in[12];
  float* out = (float*)d_out;

  char* ws = (char*)d_ws;
  const size_t MB = 1ull << 20;
  ushort_t* qb   = (ushort_t*)(ws + 0 * MB);    // 8 MiB  [B*S, E] bf16
  ushort_t* kb   = (ushort_t*)(ws + 8 * MB);    // 8 MiB
  ushort_t* vb   = (ushort_t*)(ws + 16 * MB);   // 8 MiB
  ushort_t* wqb  = (ushort_t*)(ws + 24 * MB);   // 2 MiB  [E,E] bf16
  ushort_t* wkb  = (ushort_t*)(ws + 26 * MB);   // 2 MiB
  ushort_t* wvb  = (ushort_t*)(ws + 28 * MB);   // 2 MiB
  ushort_t* wob  = (ushort_t*)(ws + 30 * MB);   // 2 MiB
  ushort_t* Qh   = (ushort_t*)(ws + 32 * MB);   // 8 MiB  [B,H,S,D]
  ushort_t* Kh   = (ushort_t*)(ws + 40 * MB);   // 8 MiB  [B,H,S,D]
  ushort_t* Vt   = (ushort_t*)(ws + 48 * MB);   // 8 MiB  [B,H,D,S]
  ushort_t* aout = (ushort_t*)(ws + 56 * MB);   // 8 MiB  [B,S,E]
  ushort_t* bias = (ushort_t*)(ws + 64 * MB);   // 16 MiB [B,S(k),S(q)]

  convert_kernel<<<8192, 256, 0, stream>>>(query, key, value, Wq, Wk, Wv, Wo,
                                           qb, kb, vb, wqb, wkb, wvb, wob);
  bias_kernel<<<dim3(32, 32, 2), 256, 0, stream>>>(adj, mask, bias);
  qkv_kernel<<<dim3(8, 32, 3), 256, 0, stream>>>(qb, kb, vb, wqb, wkb, wvb,
                                                 bq, bk, bv, Qh, Kh, Vt);
  attn_kernel<<<dim3(32, 32), 256, 0, stream>>>(Qh, Kh, Vt, bias, aout);
  oproj_kernel<<<dim3(16, 32), 256, 0, stream>>>(aout, wob, bo, out);
}

// Round 6
// 310.432 us; speedup vs baseline: 1.6446x; 1.6446x over previous
//
#include <hip/hip_runtime.h>

// GraphAttention on MI355X (gfx950).  B=2, S=2048, E=1024, H=16, D=64.
// Round 6 = round-4 structure (LDS-staged K/V, q-tile 64, 4 blocks/CU) with
// XOR-swizzled LDS layouts (16B-chunk granularity) for Ks/Vts/Ps:
// all fragment reads and Ps writes drop to 2-way bank aliasing (free),
// while global_load_lds destinations stay contiguous (HW constraint).

typedef unsigned short ushort_t;
typedef __attribute__((ext_vector_type(8))) short bf16x8;
typedef __attribute__((ext_vector_type(4))) float floatx4;

#define NB 2
#define NS 2048
#define NE 1024
#define NH 16
#define ND 64

__device__ __forceinline__ unsigned short f2bf(float f) {
  unsigned int u = __float_as_uint(f);
  return (unsigned short)((u + 0x7fffu + ((u >> 16) & 1u)) >> 16);
}
__device__ __forceinline__ float bf2f(unsigned short h) {
  return __uint_as_float(((unsigned int)h) << 16);
}

__device__ __forceinline__ void gload_lds16(const void* g, void* l) {
  __builtin_amdgcn_global_load_lds(
      (const __attribute__((address_space(1))) unsigned int*)g,
      (__attribute__((address_space(3))) unsigned int*)l, 16, 0, 0);
}

// ---------------------------------------------------------------------------
// Kernel 1: fp32->bf16 conversions + fused (adj, mask) -> bias[b][q][k] bf16.
// ---------------------------------------------------------------------------
__global__ __launch_bounds__(256) void convert_kernel(
    const float* __restrict__ q, const float* __restrict__ k, const float* __restrict__ v,
    const float* __restrict__ wq, const float* __restrict__ wk,
    const float* __restrict__ wv, const float* __restrict__ wo,
    const float* __restrict__ adj, const int* __restrict__ mask,
    ushort_t* __restrict__ qb, ushort_t* __restrict__ kb, ushort_t* __restrict__ vb,
    ushort_t* __restrict__ wqb, ushort_t* __restrict__ wkb,
    ushort_t* __restrict__ wvb, ushort_t* __restrict__ wob,
    ushort_t* __restrict__ bias)
{
  const long U1 = (long)NB * NS * NE / 8;  // 524288
  const long U2 = (long)NE * NE / 8;       // 131072
  long idx = (long)blockIdx.x * 256 + threadIdx.x;
  const float* src;
  ushort_t* dst;
  if (idx < U1) { src = q; dst = qb; }
  else if ((idx -= U1) < U1) { src = k; dst = kb; }
  else if ((idx -= U1) < U1) { src = v; dst = vb; }
  else if ((idx -= U1) < U2) { src = wq; dst = wqb; }
  else if ((idx -= U2) < U2) { src = wk; dst = wkb; }
  else if ((idx -= U2) < U2) { src = wv; dst = wvb; }
  else if ((idx -= U2) < U2) { src = wo; dst = wob; }
  else {
    idx -= U2;  // bias unit index in [0, B*S*S/8)
    long flat = idx * 8;
    long rem = flat & ((1L << 22) - 1);
    const float4* a4 = (const float4*)(adj + rem);
    const int4* m4 = (const int4*)(mask + flat);
    float4 a0 = a4[0], a1 = a4[1];
    int4 m0 = m4[0], m1 = m4[1];
    const float NEGV = -1e30f;
    union { ushort_t us[8]; uint4 v4; } o;
    o.us[0] = f2bf(m0.x ? a0.x : NEGV);
    o.us[1] = f2bf(m0.y ? a0.y : NEGV);
    o.us[2] = f2bf(m0.z ? a0.z : NEGV);
    o.us[3] = f2bf(m0.w ? a0.w : NEGV);
    o.us[4] = f2bf(m1.x ? a1.x : NEGV);
    o.us[5] = f2bf(m1.y ? a1.y : NEGV);
    o.us[6] = f2bf(m1.z ? a1.z : NEGV);
    o.us[7] = f2bf(m1.w ? a1.w : NEGV);
    ((uint4*)bias)[idx] = o.v4;
    return;
  }
  const float4* s4 = (const float4*)src;
  float4 a0 = s4[idx * 2], a1 = s4[idx * 2 + 1];
  union { ushort_t us[8]; uint4 v4; } o;
  o.us[0] = f2bf(a0.x); o.us[1] = f2bf(a0.y); o.us[2] = f2bf(a0.z); o.us[3] = f2bf(a0.w);
  o.us[4] = f2bf(a1.x); o.us[5] = f2bf(a1.y); o.us[6] = f2bf(a1.z); o.us[7] = f2bf(a1.w);
  ((uint4*)dst)[idx] = o.v4;
}

// ---------------------------------------------------------------------------
// Kernel 2: fused QKV projection GEMM (round-1 proven).
// ---------------------------------------------------------------------------
__global__ __launch_bounds__(256) void qkv_kernel(
    const ushort_t* __restrict__ xq, const ushort_t* __restrict__ xk, const ushort_t* __restrict__ xv,
    const ushort_t* __restrict__ wqb, const ushort_t* __restrict__ wkb, const ushort_t* __restrict__ wvb,
    const float* __restrict__ bq, const float* __restrict__ bk, const float* __restrict__ bvv,
    ushort_t* __restrict__ Qh, ushort_t* __restrict__ Kh, ushort_t* __restrict__ Vt)
{
  __shared__ __align__(16) ushort_t As[128 * 32];
  __shared__ __align__(16) ushort_t Bs[128 * 32];

  int z = blockIdx.z;
  const ushort_t* X = (z == 0) ? xq : (z == 1) ? xk : xv;
  const ushort_t* W = (z == 0) ? wqb : (z == 1) ? wkb : wvb;
  const float* bias = (z == 0) ? bq : (z == 1) ? bk : bvv;

  int t = threadIdx.x;
  int lane = t & 63, w = t >> 6;
  int quad = lane >> 4, l16 = lane & 15;
  int wr = w >> 1, wc = w & 1;
  int m0 = blockIdx.y * 128, f0 = blockIdx.x * 128;

  floatx4 acc[4][4] = {};

  int arow = t >> 2, apart = t & 3;
  const ushort_t* Xg = X + (long)(m0 + arow) * NE + apart * 8;
  const ushort_t* Wg = W + (long)(f0 + arow) * NE + apart * 8;
  ushort_t* As_t = As + t * 8;
  ushort_t* Bs_t = Bs + t * 8;

  for (int k0 = 0; k0 < NE; k0 += 32) {
    __syncthreads();
    gload_lds16(Xg + k0, As_t);
    gload_lds16(Xg + k0 + 64 * NE, As_t + 64 * 32);
    gload_lds16(Wg + k0, Bs_t);
    gload_lds16(Wg + k0 + 64 * NE, Bs_t + 64 * 32);
    __syncthreads();
    bf16x8 af[4], bf[4];
#pragma unroll
    for (int i = 0; i < 4; i++)
      af[i] = *(const bf16x8*)(As + (wr * 64 + i * 16 + l16) * 32 + quad * 8);
#pragma unroll
    for (int j = 0; j < 4; j++)
      bf[j] = *(const bf16x8*)(Bs + (wc * 64 + j * 16 + l16) * 32 + quad * 8);
#pragma unroll
    for (int i = 0; i < 4; i++)
#pragma unroll
      for (int j = 0; j < 4; j++)
        acc[i][j] = __builtin_amdgcn_mfma_f32_16x16x32_bf16(af[i], bf[j], acc[i][j], 0, 0, 0);
  }

  ushort_t* Out = (z == 0) ? Qh : (z == 1) ? Kh : Vt;
  bool isV = (z == 2);
#pragma unroll
  for (int j = 0; j < 4; j++) {
    int f = f0 + wc * 64 + j * 16 + l16;
    float bval = bias[f];
    int h = f >> 6, d = f & 63;
#pragma unroll
    for (int i = 0; i < 4; i++) {
      int mbase = m0 + wr * 64 + i * 16 + quad * 4;
#pragma unroll
      for (int r = 0; r < 4; r++) {
        int m = mbase + r;
        int b = m >> 11, s = m & 2047;
        float y = acc[i][j][r] + bval;
        long off;
        if (!isV) off = ((long)(b * NH + h) * NS + s) * ND + d;       // [B,H,S,D]
        else      off = ((long)(b * NH + h) * ND + d) * NS + s;       // [B,H,D,S]
        Out[off] = f2bf(y);
      }
    }
  }
}

// ---------------------------------------------------------------------------
// Kernel 3: flash attention, max-free, XOR-swizzled LDS.
// Block 256 (4 waves), q-tile 64 (16 rows/wave), k-tiles of 32.
// Swizzle scheme (16B chunks): chunk (row-group, c) stored at c' = c ^ (g&7)
// where g indexes 128B groups. All frag reads + Ps writes -> 2-way (free).
// Grid (32 qt, 32 bh) = 1024 blocks = 4 blocks/CU.
// ---------------------------------------------------------------------------
__global__ __launch_bounds__(256) void attn_kernel(
    const ushort_t* __restrict__ Qh, const ushort_t* __restrict__ Kh,
    const ushort_t* __restrict__ Vt, const ushort_t* __restrict__ bias,
    ushort_t* __restrict__ aout)
{
  __shared__ __align__(16) ushort_t Qs[64 * 64];    // 8KB  (unswizzled; read twice)
  __shared__ __align__(16) ushort_t Ks[32 * 64];    // 4KB  [row r][chunk c^(r&7)]
  __shared__ __align__(16) ushort_t Vts[64 * 32];   // 4KB  [superrow sr][chunk c^(sr&7)]
  __shared__ __align__(16) ushort_t Ps[4][16 * 32]; // 4KB  per-wave, superrow-swizzled

  int t = threadIdx.x, lane = t & 63, w = t >> 6;
  int quad = lane >> 4, l16 = lane & 15;
  int qt = blockIdx.x;       // q-tile 0..31
  int bh = blockIdx.y;       // 0..31
  int bb = bh >> 4, h = bh & 15;
  int q0 = qt * 64;

  // stage Q tile (once): 64 rows x 64 cols
  const ushort_t* Qg = Qh + ((long)bh * NS + q0) * ND;
#pragma unroll
  for (int c = 0; c < 2; c++) {
    int idx = c * 256 + t;
    int row = idx >> 3, part = idx & 7;
    gload_lds16(Qg + (long)row * ND + part * 8, Qs + idx * 8);
  }
  __syncthreads();

  bf16x8 aq[2];
#pragma unroll
  for (int kd = 0; kd < 2; kd++)
    aq[kd] = *(const bf16x8*)(Qs + (w * 16 + l16) * 64 + kd * 32 + quad * 8);

  floatx4 acc[4] = {};
  float lsum[4] = {0.f, 0.f, 0.f, 0.f};

  const ushort_t* Kg = Kh + (long)bh * NS * ND;
  const ushort_t* Vg = Vt + (long)bh * ND * NS;
  const ushort_t* biasg = bias + (long)bb * NS * NS;

  // K staging: thread t -> LDS chunk t. row = t>>3, dest chunk c' = t&7,
  // source chunk c = c' ^ (row&7).
  int krow = t >> 3;
  int kc = (t & 7) ^ (krow & 7);
  // V staging: superrow sr = t>>3 (2 d-rows), dest chunk c' = t&7,
  // source chunk c = c' ^ (sr&7); d-row = sr*2 + (c>>2), in-row chunk = c&3.
  int vsr = t >> 3;
  int vc = (t & 7) ^ (vsr & 7);
  int vrow = vsr * 2 + (vc >> 2);
  int vpart = vc & 3;

  // per-lane swizzled LDS read offsets (loop-invariant)
  const int ks_x = l16 & 7;                 // Ks row-xor
  const int vs_c = (((l16 & 1) * 4 + quad) ^ (l16 >> 1)) * 8;  // Vts chunk off
  ushort_t* Psw = &Ps[w][0];
  const int ap_off = (l16 >> 1) * 64 + vs_c;  // Ps read: same formula as Vts

  for (int kt = 0; kt < NS / 32; kt++) {
    int k0 = kt * 32;
    __syncthreads();
    gload_lds16(Kg + (long)(k0 + krow) * ND + kc * 8, Ks + t * 8);
    gload_lds16(Vg + (long)vrow * NS + k0 + vpart * 8, Vts + t * 8);
    __syncthreads();

    // K fragments: bk[jk][kd] = K[k0+jk*16+l16][kd*32+quad*8 ..+8]
    bf16x8 bk[2][2];
#pragma unroll
    for (int jk = 0; jk < 2; jk++)
#pragma unroll
      for (int kd = 0; kd < 2; kd++)
        bk[jk][kd] = *(const bf16x8*)(Ks + (jk * 16 + l16) * 64
                                         + ((kd * 4 + quad) ^ ks_x) * 8);
    // V fragments: bv[j] = Vt[j*16+l16][k0+quad*8 ..+8]
    bf16x8 bv[4];
#pragma unroll
    for (int j = 0; j < 4; j++)
      bv[j] = *(const bf16x8*)(Vts + (j * 8 + (l16 >> 1)) * 64 + vs_c);

    // scores = Q K^T  (C rows: q = quad*4 + r, cols: k = jk*16 + l16)
    floatx4 sc[2] = {};
#pragma unroll
    for (int jk = 0; jk < 2; jk++)
#pragma unroll
      for (int kd = 0; kd < 2; kd++)
        sc[jk] = __builtin_amdgcn_mfma_f32_16x16x32_bf16(aq[kd], bk[jk][kd], sc[jk], 0, 0, 0);

    // bias + p = exp(sc/8 + bias); no running max (bounded scores)
    int qg = q0 + w * 16 + quad * 4;
    float bsv[2][4];
#pragma unroll
    for (int r = 0; r < 4; r++)
#pragma unroll
      for (int jk = 0; jk < 2; jk++)
        bsv[jk][r] = bf2f(biasg[(long)(qg + r) * NS + k0 + jk * 16 + l16]);
    float p[2][4];
#pragma unroll
    for (int r = 0; r < 4; r++) {
      float s0 = sc[0][r] * 0.125f + bsv[0][r];
      float s1 = sc[1][r] * 0.125f + bsv[1][r];
      float p0 = __expf(s0);
      float p1 = __expf(s1);
      lsum[r] += p0 + p1;
      p[0][r] = p0;
      p[1][r] = p1;
    }

    // P: C/D layout -> per-wave swizzled LDS -> A layout.
    // value (q=quad*4+r, col=jk*16+l16): sr = q>>1, c = (r&1)*4 + jk*2 + (l16>>3),
    // store at sr*64 + (c^sr)*8 + (l16&7).
#pragma unroll
    for (int jk = 0; jk < 2; jk++)
#pragma unroll
      for (int r = 0; r < 4; r++) {
        int sr = quad * 2 + (r >> 1);
        int c = (r & 1) * 4 + jk * 2 + (l16 >> 3);
        Psw[sr * 64 + (c ^ sr) * 8 + (l16 & 7)] = f2bf(p[jk][r]);
      }
    asm volatile("s_waitcnt lgkmcnt(0)" ::: "memory");

    bf16x8 ap = *(const bf16x8*)(Psw + ap_off);
#pragma unroll
    for (int j = 0; j < 4; j++)
      acc[j] = __builtin_amdgcn_mfma_f32_16x16x32_bf16(ap, bv[j], acc[j], 0, 0, 0);
  }

  // deferred row-sum reduction: butterfly over l16 (rows live in quad groups)
#pragma unroll
  for (int r = 0; r < 4; r++) {
    float s = lsum[r];
    s += __shfl_xor(s, 1);
    s += __shfl_xor(s, 2);
    s += __shfl_xor(s, 4);
    s += __shfl_xor(s, 8);
    lsum[r] = s;
  }

  // epilogue: O / l -> aout [B,S,E] bf16
  ushort_t* og = aout + (long)bb * NS * NE + h * ND;
#pragma unroll
  for (int r = 0; r < 4; r++) {
    int qg = q0 + w * 16 + quad * 4 + r;
    float inv = 1.0f / lsum[r];
#pragma unroll
    for (int j = 0; j < 4; j++) {
      int d = j * 16 + l16;
      og[(long)qg * NE + d] = f2bf(acc[j][r] * inv);
    }
  }
}

// ---------------------------------------------------------------------------
// Kernel 4: output projection. out = aout @ Wo^T + bo, fp32 stores.
// 128m x 64n tiles, grid (16, 32) = 512 blocks = 2/CU.
// ---------------------------------------------------------------------------
__global__ __launch_bounds__(256) void oproj_kernel(
    const ushort_t* __restrict__ A, const ushort_t* __restrict__ Wob,
    const float* __restrict__ bo, float* __restrict__ out)
{
  __shared__ __align__(16) ushort_t As[128 * 32];  // 8KB
  __shared__ __align__(16) ushort_t Bs[64 * 32];   // 4KB

  int t = threadIdx.x;
  int lane = t & 63, w = t >> 6;
  int quad = lane >> 4, l16 = lane & 15;
  int wr = w >> 1, wc = w & 1;
  int m0 = blockIdx.y * 128, f0 = blockIdx.x * 64;

  floatx4 acc[4][2] = {};
  int arow = t >> 2, apart = t & 3;
  const ushort_t* Xg = A + (long)(m0 + arow) * NE + apart * 8;
  const ushort_t* Wg = Wob + (long)(f0 + arow) * NE + apart * 8;
  ushort_t* As_t = As + t * 8;
  ushort_t* Bs_t = Bs + t * 8;
  bool bstage = (arow < 64);

  for (int k0 = 0; k0 < NE; k0 += 32) {
    __syncthreads();
    gload_lds16(Xg + k0, As_t);
    gload_lds16(Xg + k0 + 64 * NE, As_t + 64 * 32);
    if (bstage) gload_lds16(Wg + k0, Bs_t);
    __syncthreads();
    bf16x8 af[4], bf[2];
#pragma unroll
    for (int i = 0; i < 4; i++)
      af[i] = *(const bf16x8*)(As + (wr * 64 + i * 16 + l16) * 32 + quad * 8);
#pragma unroll
    for (int j = 0; j < 2; j++)
      bf[j] = *(const bf16x8*)(Bs + (wc * 32 + j * 16 + l16) * 32 + quad * 8);
#pragma unroll
    for (int i = 0; i < 4; i++)
#pragma unroll
      for (int j = 0; j < 2; j++)
        acc[i][j] = __builtin_amdgcn_mfma_f32_16x16x32_bf16(af[i], bf[j], acc[i][j], 0, 0, 0);
  }

#pragma unroll
  for (int j = 0; j < 2; j++) {
    int f = f0 + wc * 32 + j * 16 + l16;
    float bval = bo[f];
#pragma unroll
    for (int i = 0; i < 4; i++) {
      int mbase = m0 + wr * 64 + i * 16 + quad * 4;
#pragma unroll
      for (int r = 0; r < 4; r++) {
        int m = mbase + r;
        out[(long)m * NE + f] = acc[i][j][r] + bval;
      }
    }
  }
}

// ---------------------------------------------------------------------------
extern "C" void kernel_launch(void* const* d_in, const int* in_sizes, int n_in,
                              void* d_out, int out_size, void* d_ws, size_t ws_size,
                              hipStream_t stream) {
  const float* query = (const float*)d_in[0];
  const float* key   = (const float*)d_in[1];
  const float* value = (const float*)d_in[2];
  const float* adj   = (const float*)d_in[3];
  const int*   mask  = (const int*)d_in[4];
  const float* Wq = (const float*)d_in[5];
  const float* bq = (const float*)d_in[6];
  const float* Wk = (const float*)d_in[7];
  const float* bk = (const float*)d_in[8];
  const float* Wv = (const float*)d_in[9];
  const float* bv = (const float*)d_in[10];
  const float* Wo = (const float*)d_in[11];
  const float* bo = (const float*)d_in[12];
  float* out = (float*)d_out;

  char* ws = (char*)d_ws;
  const size_t MB = 1ull << 20;
  ushort_t* qb   = (ushort_t*)(ws + 0 * MB);    // 8 MiB  [B*S, E] bf16
  ushort_t* kb   = (ushort_t*)(ws + 8 * MB);    // 8 MiB
  ushort_t* vb   = (ushort_t*)(ws + 16 * MB);   // 8 MiB
  ushort_t* wqb  = (ushort_t*)(ws + 24 * MB);   // 2 MiB  [E,E] bf16
  ushort_t* wkb  = (ushort_t*)(ws + 26 * MB);   // 2 MiB
  ushort_t* wvb  = (ushort_t*)(ws + 28 * MB);   // 2 MiB
  ushort_t* wob  = (ushort_t*)(ws + 30 * MB);   // 2 MiB
  ushort_t* Qh   = (ushort_t*)(ws + 32 * MB);   // 8 MiB  [B,H,S,D]
  ushort_t* Kh   = (ushort_t*)(ws + 40 * MB);   // 8 MiB  [B,H,S,D]
  ushort_t* Vt   = (ushort_t*)(ws + 48 * MB);   // 8 MiB  [B,H,D,S]
  ushort_t* aout = (ushort_t*)(ws + 56 * MB);   // 8 MiB  [B,S,E]
  ushort_t* bias = (ushort_t*)(ws + 64 * MB);   // 16 MiB [B,S,S]

  convert_kernel<<<12288, 256, 0, stream>>>(query, key, value, Wq, Wk, Wv, Wo,
                                            adj, mask, qb, kb, vb, wqb, wkb, wvb, wob, bias);
  qkv_kernel<<<dim3(8, 32, 3), 256, 0, stream>>>(qb, kb, vb, wqb, wkb, wvb,
                                                 bq, bk, bv, Qh, Kh, Vt);
  attn_kernel<<<dim3(32, 32), 256, 0, stream>>>(Qh, Kh, Vt, bias, aout);
  oproj_kernel<<<dim3(16, 32), 256, 0, stream>>>(aout, wob, bo, out);
}